// Round 1
// baseline (269.171 us; speedup 1.0000x reference)
//
#include <hip/hip_runtime.h>
#include <math.h>

// Problem constants
#define NTOT 4608      // N_IN * DIM * DIM
#define NC   16        // n positions per phase1 block
#define BC   32        // batch items per phase1 block
#define NBN  (NTOT / NC)   // 288 n-chunks
#define NBB  (128 / BC)    // 4 b-chunks

// w_lds layout: row (o,j) holds d=0..7, with +4-float skew per o to break
// the 640B-stride bank conflict across og lanes. Row start (floats):
__device__ __forceinline__ int wrow_off(int o, int j) { return (o * 10 + j) * 8 + o * 4; }

// --- One-time weight transpose: Wt[n*1280 + (o*10+j)*8 + d] = W[(d*16+o)*46080 + n*10 + j]
__global__ __launch_bounds__(256) void transpose_w_kernel(const float* __restrict__ W,
                                                          float* __restrict__ Wt) {
    const unsigned r = blockIdx.x * 256u + threadIdx.x;   // < 4608*160 = 737280
    const unsigned n   = r / 160u;
    const unsigned ojr = r % 160u;
    const unsigned o   = ojr / 10u;
    const unsigned j   = ojr % 10u;
    float vals[8];
    #pragma unroll
    for (int d = 0; d < 8; ++d)
        vals[d] = W[(size_t)(d * 16 + o) * (NTOT * 10) + (size_t)n * 10 + j];
    float* dst = Wt + (size_t)n * 1280 + ojr * 8;
    *reinterpret_cast<float4*>(dst)     = make_float4(vals[0], vals[1], vals[2], vals[3]);
    *reinterpret_cast<float4*>(dst + 4) = make_float4(vals[4], vals[5], vals[6], vals[7]);
}

// --- Phase 1: per (n-chunk, b-chunk): recompute u_hat, softmax(c), accumulate partial s
// Thread map: tid = b_l*8 + og  (og = o-pair index 0..7, b_l = 0..31)
template<bool FIRST>
__global__ __launch_bounds__(256) void phase1_kernel(
    const float* __restrict__ x, const float* __restrict__ Wt,
    const float* __restrict__ A, float* __restrict__ partial)
{
    __shared__ float u_lds[NC][BC * 8];      // [n_local][b_l*8+d]  16 KB
    __shared__ float w_lds[1280 + 64];       // skewed rows, max off 1332+8

    const int tid = threadIdx.x;
    const int nb = blockIdx.x, bb = blockIdx.y;
    const int n0 = nb * NC;
    const int og  = tid & 7;
    const int b_l = tid >> 3;
    const int b_g = bb * BC + b_l;

    // stage u: thread p loads 16 consecutive n for one (b,d) row of x
    {
        const int d = tid & 7, bl2 = tid >> 3;
        const float* src = x + (size_t)((bb * BC + bl2) * 8 + d) * NTOT + n0;
        #pragma unroll
        for (int q = 0; q < NC / 4; ++q) {
            float4 v = *reinterpret_cast<const float4*>(src + q * 4);
            u_lds[q * 4 + 0][tid] = v.x;
            u_lds[q * 4 + 1][tid] = v.y;
            u_lds[q * 4 + 2][tid] = v.z;
            u_lds[q * 4 + 3][tid] = v.w;
        }
    }

    float A_reg[2][10];
    if (!FIRST) {
        #pragma unroll
        for (int oo = 0; oo < 2; ++oo)
            #pragma unroll
            for (int j = 0; j < 10; ++j)
                A_reg[oo][j] = A[((size_t)b_g * 16 + og * 2 + oo) * 10 + j];
    }

    float P[2][10] = {};

    for (int nl = 0; nl < NC; ++nl) {
        __syncthreads();
        // stage W slice for n = n0+nl: 160 rows x 8 floats (skewed)
        if (tid < 160) {
            const float* wsrc = Wt + (size_t)(n0 + nl) * 1280 + tid * 8;
            float4 a = *reinterpret_cast<const float4*>(wsrc);
            float4 b = *reinterpret_cast<const float4*>(wsrc + 4);
            const int o = tid / 10;
            float* wdst = &w_lds[tid * 8 + o * 4];
            *reinterpret_cast<float4*>(wdst)     = a;
            *reinterpret_cast<float4*>(wdst + 4) = b;
        }
        __syncthreads();

        float ureg[8];
        #pragma unroll
        for (int d = 0; d < 8; ++d) ureg[d] = u_lds[nl][b_l * 8 + d];

        // u_hat for this thread's 2 output capsules, all 10 j
        float uh[2][10];
        #pragma unroll
        for (int oo = 0; oo < 2; ++oo) {
            const int o = og * 2 + oo;
            #pragma unroll
            for (int j = 0; j < 10; ++j) {
                const float* w = &w_lds[wrow_off(o, j)];
                float acc = ureg[0] * w[0];
                #pragma unroll
                for (int d = 1; d < 8; ++d) acc = fmaf(ureg[d], w[d], acc);
                uh[oo][j] = acc;
            }
        }

        float c[10];
        if (FIRST) {
            #pragma unroll
            for (int j = 0; j < 10; ++j) c[j] = 0.1f;   // softmax of zero logits
        } else {
            float vp[10];
            #pragma unroll
            for (int j = 0; j < 10; ++j)
                vp[j] = fmaf(A_reg[0][j], uh[0][j], A_reg[1][j] * uh[1][j]);
            // reduce over the 8 og lanes (lane bits 0..2)
            #pragma unroll
            for (int m = 1; m <= 4; m <<= 1)
                #pragma unroll
                for (int j = 0; j < 10; ++j)
                    vp[j] += __shfl_xor(vp[j], m, 64);
            float mx = vp[0];
            #pragma unroll
            for (int j = 1; j < 10; ++j) mx = fmaxf(mx, vp[j]);
            float sum = 0.f;
            #pragma unroll
            for (int j = 0; j < 10; ++j) { c[j] = __expf(vp[j] - mx); sum += c[j]; }
            const float inv = 1.0f / sum;
            #pragma unroll
            for (int j = 0; j < 10; ++j) c[j] *= inv;
        }

        #pragma unroll
        for (int oo = 0; oo < 2; ++oo)
            #pragma unroll
            for (int j = 0; j < 10; ++j)
                P[oo][j] = fmaf(c[j], uh[oo][j], P[oo][j]);
    }

    float* dst = partial + ((size_t)nb * 128 + b_g) * 160 + og * 20;
    #pragma unroll
    for (int oo = 0; oo < 2; ++oo)
        #pragma unroll
        for (int j = 0; j < 10; ++j)
            dst[oo * 10 + j] = P[oo][j];
}

// --- Phase 2: per-b reduce partials over NBN chunks, squash, update A / write out
template<bool FIRST, bool LAST>
__global__ __launch_bounds__(256) void phase2_kernel(
    const float* __restrict__ partial, float* __restrict__ A, float* __restrict__ out)
{
    const int b = blockIdx.x;
    const int k = threadIdx.x;       // k < 160: (o,j) = (k/10, k%10)
    __shared__ float sraw[160];
    float acc = 0.f;
    if (k < 160) {
        const float* p = partial + (size_t)b * 160 + k;
        #pragma unroll 8
        for (int nb = 0; nb < NBN; ++nb) acc += p[(size_t)nb * 128 * 160];
        sraw[k] = acc;
    }
    __syncthreads();
    if (k < 160) {
        const int j = k % 10;
        float ssq = 0.f;
        #pragma unroll
        for (int o = 0; o < 16; ++o) { float v = sraw[o * 10 + j]; ssq = fmaf(v, v, ssq); }
        const float scale = ssq / ((1.f + ssq) * sqrtf(ssq));
        const float s = acc * scale;
        if (LAST) {
            out[(size_t)b * 160 + k] = s;
        } else if (FIRST) {
            A[(size_t)b * 160 + k] = s;       // no read: first write each launch
        } else {
            A[(size_t)b * 160 + k] += s;
        }
    }
}

extern "C" void kernel_launch(void* const* d_in, const int* in_sizes, int n_in,
                              void* d_out, int out_size, void* d_ws, size_t ws_size,
                              hipStream_t stream) {
    const float* x = (const float*)d_in[0];     // (128, 8, 32, 12, 12)
    const float* W = (const float*)d_in[1];     // (8, 16, 4608, 10)
    float* out = (float*)d_out;                 // (128, 16, 10)
    float* ws  = (float*)d_ws;

    float* Wt      = ws;                               // 4608*1280          = 5,898,240 f
    float* A       = Wt + (size_t)NTOT * 1280;         // 128*160            = 20,480 f
    float* partial = A + 128 * 160;                    // 288*128*160        = 5,898,240 f
    // total ws: ~47.3 MB

    transpose_w_kernel<<<2880, 256, 0, stream>>>(W, Wt);

    dim3 g1(NBN, NBB);
    phase1_kernel<true ><<<g1, 256, 0, stream>>>(x, Wt, A, partial);
    phase2_kernel<true , false><<<128, 256, 0, stream>>>(partial, A, out);
    phase1_kernel<false><<<g1, 256, 0, stream>>>(x, Wt, A, partial);
    phase2_kernel<false, false><<<128, 256, 0, stream>>>(partial, A, out);
    phase1_kernel<false><<<g1, 256, 0, stream>>>(x, Wt, A, partial);
    phase2_kernel<false, true ><<<128, 256, 0, stream>>>(partial, A, out);
}